// Round 1
// baseline (2518.357 us; speedup 1.0000x reference)
//
#include <hip/hip_runtime.h>
#include <hip/hip_bf16.h>

// Problem dims
#define T_LEN   16384
#define HID     1024
#define IN_DIM  1024
#define OUT_DIM 1024

// Scan chunking
#define CHUNK   128
#define NCHUNK  128   // T_LEN / CHUNK

// GEMM tiling
#define KT      16
#define LDSP    68    // 64 + 4 pad: conflict-free transposed stores, 16B-aligned rows

// ---------------- prep: lambda (complex), exp(gamma) ----------------
__global__ __launch_bounds__(256) void prep_kernel(
    const float* __restrict__ nu_log, const float* __restrict__ theta_log,
    const float* __restrict__ gamma_log,
    float* __restrict__ lam_re, float* __restrict__ lam_im, float* __restrict__ eg) {
  int h = blockIdx.x * 256 + threadIdx.x;
  if (h < HID) {
    float mag = expf(-expf(nu_log[h]));
    float th  = expf(theta_log[h]);
    lam_re[h] = mag * cosf(th);
    lam_im[h] = mag * sinf(th);
    eg[h]     = expf(gamma_log[h]);
  }
}

// ---------------- GEMM 1: Bu = (X * eg[i]) @ (B_re | B_im) ----------------
// A: inputs (T x IN), scaled per-row-of-B (i.e. per k) by eg[k]. B: (IN x HID), n-contiguous.
__global__ __launch_bounds__(256) void bu_gemm(
    const float* __restrict__ X,
    const float* __restrict__ Bre, const float* __restrict__ Bim,
    const float* __restrict__ eg,
    float* __restrict__ BuRe, float* __restrict__ BuIm) {
  __shared__ float As[KT][LDSP];     // transposed: As[k][m]
  __shared__ float BsR[KT][LDSP];
  __shared__ float BsI[KT][LDSP];
  int tid = threadIdx.x;
  int tb = blockIdx.x * 64;
  int hb = blockIdx.y * 64;
  int tx = tid & 15, ty = tid >> 4;
  float acc_re[4][4] = {{0.f}}, acc_im[4][4] = {{0.f}};

  for (int k0 = 0; k0 < IN_DIM; k0 += KT) {
#pragma unroll
    for (int r = 0; r < 4; ++r) {          // A: 64x16, k-inner global reads
      int idx = r * 256 + tid;
      int m = idx >> 4, k = idx & 15;
      As[k][m] = X[(size_t)(tb + m) * IN_DIM + k0 + k] * eg[k0 + k];
    }
#pragma unroll
    for (int r = 0; r < 4; ++r) {          // B: 16x64, n-inner (fully coalesced)
      int idx = r * 256 + tid;
      int k = idx >> 6, n = idx & 63;
      BsR[k][n] = Bre[(size_t)(k0 + k) * HID + hb + n];
      BsI[k][n] = Bim[(size_t)(k0 + k) * HID + hb + n];
    }
    __syncthreads();
#pragma unroll
    for (int k = 0; k < KT; ++k) {
      float a[4], br[4], bi[4];
#pragma unroll
      for (int j = 0; j < 4; ++j) {
        a[j]  = As[k][ty * 4 + j];
        br[j] = BsR[k][tx * 4 + j];
        bi[j] = BsI[k][tx * 4 + j];
      }
#pragma unroll
      for (int i = 0; i < 4; ++i)
#pragma unroll
        for (int j = 0; j < 4; ++j) {
          acc_re[i][j] = fmaf(a[i], br[j], acc_re[i][j]);
          acc_im[i][j] = fmaf(a[i], bi[j], acc_im[i][j]);
        }
    }
    __syncthreads();
  }
#pragma unroll
  for (int i = 0; i < 4; ++i) {
    size_t t = tb + ty * 4 + i;
#pragma unroll
    for (int j = 0; j < 4; ++j) {
      size_t h = hb + tx * 4 + j;
      BuRe[t * HID + h] = acc_re[i][j];
      BuIm[t * HID + h] = acc_im[i][j];
    }
  }
}

// ---------------- scan pass 1: in-place local scans, write chunk sums ----------------
__global__ __launch_bounds__(256) void scan_local(
    float* __restrict__ BuRe, float* __restrict__ BuIm,
    const float* __restrict__ lam_re, const float* __restrict__ lam_im,
    float* __restrict__ Sre, float* __restrict__ Sim) {
  int h = blockIdx.y * 256 + threadIdx.x;
  int c = blockIdx.x;
  float lr = lam_re[h], li = lam_im[h];
  float hr = 0.f, hi = 0.f;
  size_t base = (size_t)c * CHUNK * HID + h;
  for (int t = 0; t < CHUNK; ++t) {
    float br = BuRe[base + (size_t)t * HID];
    float bi = BuIm[base + (size_t)t * HID];
    float nr = fmaf(lr, hr, fmaf(-li, hi, br));
    float ni = fmaf(lr, hi, fmaf(li, hr, bi));
    BuRe[base + (size_t)t * HID] = nr;
    BuIm[base + (size_t)t * HID] = ni;
    hr = nr; hi = ni;
  }
  Sre[(size_t)c * HID + h] = hr;
  Sim[(size_t)c * HID + h] = hi;
}

// ---------------- scan pass 2: serial carry scan over chunks ----------------
__global__ __launch_bounds__(256) void scan_carry(
    const float* __restrict__ Sre, const float* __restrict__ Sim,
    const float* __restrict__ lam_re, const float* __restrict__ lam_im,
    float* __restrict__ Pre, float* __restrict__ Pim) {
  int h = blockIdx.x * 256 + threadIdx.x;
  float lr = lam_re[h], li = lam_im[h];
  // lambda^CHUNK, CHUNK = 2^7 -> 7 squarings
  float pr = lr, pi = li;
#pragma unroll
  for (int s = 0; s < 7; ++s) {
    float nr = pr * pr - pi * pi;
    float ni = 2.f * pr * pi;
    pr = nr; pi = ni;
  }
  float cr = 0.f, ci = 0.f;
  for (int c = 0; c < NCHUNK; ++c) {
    Pre[(size_t)c * HID + h] = cr;
    Pim[(size_t)c * HID + h] = ci;
    float sr = Sre[(size_t)c * HID + h];
    float si = Sim[(size_t)c * HID + h];
    float nr = fmaf(pr, cr, fmaf(-pi, ci, sr));
    float ni = fmaf(pr, ci, fmaf(pi, cr, si));
    cr = nr; ci = ni;
  }
}

// ---------------- scan pass 3: add lambda^(j+1) * carry to each local state ----------------
__global__ __launch_bounds__(256) void scan_fix(
    float* __restrict__ Hre, float* __restrict__ Him,
    const float* __restrict__ lam_re, const float* __restrict__ lam_im,
    const float* __restrict__ Pre, const float* __restrict__ Pim) {
  int h = blockIdx.y * 256 + threadIdx.x;
  int c = blockIdx.x + 1;   // chunk 0 has zero carry
  float lr = lam_re[h], li = lam_im[h];
  float qr = Pre[(size_t)c * HID + h];
  float qi = Pim[(size_t)c * HID + h];
  size_t base = (size_t)c * CHUNK * HID + h;
  for (int t = 0; t < CHUNK; ++t) {
    float nr = lr * qr - li * qi;
    float ni = lr * qi + li * qr;
    qr = nr; qi = ni;
    Hre[base + (size_t)t * HID] += qr;
    Him[base + (size_t)t * HID] += qi;
  }
}

// ---------------- GEMM 2: out = Hre@Cre^T - Him@Cim^T + X@D ----------------
__global__ __launch_bounds__(256) void out_gemm(
    const float* __restrict__ Hre, const float* __restrict__ Him,
    const float* __restrict__ Cre, const float* __restrict__ Cim,
    const float* __restrict__ X,   const float* __restrict__ D,
    float* __restrict__ out) {
  __shared__ float As1[KT][LDSP], As2[KT][LDSP];
  __shared__ float Bs1[KT][LDSP], Bs2[KT][LDSP];
  int tid = threadIdx.x;
  int tb = blockIdx.x * 64;
  int ob = blockIdx.y * 64;
  int tx = tid & 15, ty = tid >> 4;
  float acc[4][4] = {{0.f}};

  // phase 1: hidden @ C^T (C stored o-major: element (k,n) = C[(ob+n)*HID + k0+k])
  for (int k0 = 0; k0 < HID; k0 += KT) {
#pragma unroll
    for (int r = 0; r < 4; ++r) {
      int idx = r * 256 + tid;
      int m = idx >> 4, k = idx & 15;
      As1[k][m] = Hre[(size_t)(tb + m) * HID + k0 + k];
      As2[k][m] = Him[(size_t)(tb + m) * HID + k0 + k];
    }
#pragma unroll
    for (int r = 0; r < 4; ++r) {
      int idx = r * 256 + tid;
      int n = idx >> 4, k = idx & 15;   // k-inner for contiguous C rows
      Bs1[k][n] = Cre[(size_t)(ob + n) * HID + k0 + k];
      Bs2[k][n] = Cim[(size_t)(ob + n) * HID + k0 + k];
    }
    __syncthreads();
#pragma unroll
    for (int k = 0; k < KT; ++k) {
      float a1[4], a2[4], b1[4], b2[4];
#pragma unroll
      for (int j = 0; j < 4; ++j) {
        a1[j] = As1[k][ty * 4 + j];
        a2[j] = As2[k][ty * 4 + j];
        b1[j] = Bs1[k][tx * 4 + j];
        b2[j] = Bs2[k][tx * 4 + j];
      }
#pragma unroll
      for (int i = 0; i < 4; ++i)
#pragma unroll
        for (int j = 0; j < 4; ++j) {
          acc[i][j] = fmaf(a1[i], b1[j], acc[i][j]);
          acc[i][j] = fmaf(-a2[i], b2[j], acc[i][j]);
        }
    }
    __syncthreads();
  }

  // phase 2: + X @ D   (D indexed [i,o]: element (k,n) = D[(k0+k)*OUT + ob+n])
  for (int k0 = 0; k0 < IN_DIM; k0 += KT) {
#pragma unroll
    for (int r = 0; r < 4; ++r) {
      int idx = r * 256 + tid;
      int m = idx >> 4, k = idx & 15;
      As1[k][m] = X[(size_t)(tb + m) * IN_DIM + k0 + k];
    }
#pragma unroll
    for (int r = 0; r < 4; ++r) {
      int idx = r * 256 + tid;
      int k = idx >> 6, n = idx & 63;
      Bs1[k][n] = D[(size_t)(k0 + k) * OUT_DIM + ob + n];
    }
    __syncthreads();
#pragma unroll
    for (int k = 0; k < KT; ++k) {
      float a[4], b[4];
#pragma unroll
      for (int j = 0; j < 4; ++j) {
        a[j] = As1[k][ty * 4 + j];
        b[j] = Bs1[k][tx * 4 + j];
      }
#pragma unroll
      for (int i = 0; i < 4; ++i)
#pragma unroll
        for (int j = 0; j < 4; ++j)
          acc[i][j] = fmaf(a[i], b[j], acc[i][j]);
    }
    __syncthreads();
  }

#pragma unroll
  for (int i = 0; i < 4; ++i) {
    size_t t = tb + ty * 4 + i;
#pragma unroll
    for (int j = 0; j < 4; ++j)
      out[t * OUT_DIM + ob + tx * 4 + j] = acc[i][j];
  }
}

extern "C" void kernel_launch(void* const* d_in, const int* in_sizes, int n_in,
                              void* d_out, int out_size, void* d_ws, size_t ws_size,
                              hipStream_t stream) {
  const float* inputs    = (const float*)d_in[0];
  const float* nu_log    = (const float*)d_in[1];
  const float* theta_log = (const float*)d_in[2];
  const float* gamma_log = (const float*)d_in[3];
  const float* B_re      = (const float*)d_in[4];
  const float* B_im      = (const float*)d_in[5];
  const float* C_re      = (const float*)d_in[6];
  const float* C_im      = (const float*)d_in[7];
  const float* D         = (const float*)d_in[8];
  float* out = (float*)d_out;

  char* ws = (char*)d_ws;
  constexpr size_t TH = (size_t)T_LEN * HID;         // 16.8M floats
  constexpr size_t CH = (size_t)NCHUNK * HID;        // 131072 floats
  float* BuRe = (float*)(ws);                         // also Hre after scan
  float* BuIm = (float*)(ws + TH * 4);                // also Him
  float* Sre  = (float*)(ws + TH * 8);
  float* Sim  = (float*)(ws + TH * 8 + CH * 4);
  float* Pre  = (float*)(ws + TH * 8 + CH * 8);
  float* Pim  = (float*)(ws + TH * 8 + CH * 12);
  float* lamR = (float*)(ws + TH * 8 + CH * 16);
  float* lamI = (float*)(ws + TH * 8 + CH * 16 + 4096);
  float* eg   = (float*)(ws + TH * 8 + CH * 16 + 8192);

  prep_kernel<<<dim3(HID / 256), 256, 0, stream>>>(nu_log, theta_log, gamma_log,
                                                   lamR, lamI, eg);
  bu_gemm<<<dim3(T_LEN / 64, HID / 64), 256, 0, stream>>>(inputs, B_re, B_im, eg,
                                                          BuRe, BuIm);
  scan_local<<<dim3(NCHUNK, HID / 256), 256, 0, stream>>>(BuRe, BuIm, lamR, lamI,
                                                          Sre, Sim);
  scan_carry<<<dim3(HID / 256), 256, 0, stream>>>(Sre, Sim, lamR, lamI, Pre, Pim);
  scan_fix<<<dim3(NCHUNK - 1, HID / 256), 256, 0, stream>>>(BuRe, BuIm, lamR, lamI,
                                                            Pre, Pim);
  out_gemm<<<dim3(T_LEN / 64, OUT_DIM / 64), 256, 0, stream>>>(BuRe, BuIm, C_re, C_im,
                                                               inputs, D, out);
}

// Round 2
// 483.066 us; speedup vs baseline: 5.2133x; 5.2133x over previous
//
#include <hip/hip_runtime.h>
#include <hip/hip_bf16.h>
#include <stdint.h>

#define T_LEN   16384
#define HID     1024
#define KDIM    1024
#define CHUNK   128
#define NCHUNK  128

typedef __bf16 bf16x8 __attribute__((ext_vector_type(8)));
typedef float  f32x4  __attribute__((ext_vector_type(4)));

__device__ inline ushort f2bf(float f) {
  union { float f; uint32_t u; } v; v.f = f;
  uint32_t r = v.u + 0x7FFF + ((v.u >> 16) & 1);   // RNE
  return (ushort)(r >> 16);
}

__device__ inline void gload16(const void* g, void* l) {
  __builtin_amdgcn_global_load_lds(
      (const __attribute__((address_space(1))) void*)g,
      (__attribute__((address_space(3))) void*)l, 16, 0, 0);
}

// ---------------- prep: lambda (complex), exp(gamma) ----------------
__global__ __launch_bounds__(256) void prep_kernel(
    const float* __restrict__ nu_log, const float* __restrict__ theta_log,
    const float* __restrict__ gamma_log,
    float* __restrict__ lam_re, float* __restrict__ lam_im, float* __restrict__ eg) {
  int h = blockIdx.x * 256 + threadIdx.x;
  if (h < HID) {
    float mag = expf(-expf(nu_log[h]));
    float th  = expf(theta_log[h]);
    lam_re[h] = mag * cosf(th);
    lam_im[h] = mag * sinf(th);
    eg[h]     = expf(gamma_log[h]);
  }
}

// ---------------- fp32 -> bf16 (optionally scaled), vectorized x4 ----------------
__global__ __launch_bounds__(256) void convscale(
    const float* __restrict__ src, ushort* __restrict__ dst, float s) {
  size_t i = ((size_t)blockIdx.x * 256 + threadIdx.x) * 4;
  float4 v = *(const float4*)(src + i);
  ushort4 o;
  o.x = f2bf(v.x * s); o.y = f2bf(v.y * s);
  o.z = f2bf(v.z * s); o.w = f2bf(v.w * s);
  *(ushort4*)(dst + i) = o;
}

// ---------------- transpose 1024x1024 fp32 -> bf16, optional per-k scale --------
// dst[n*1024 + k] = src[k*1024 + n] * (scale ? scale[k] : 1)
__global__ __launch_bounds__(256) void transpose_bf(
    const float* __restrict__ src, ushort* __restrict__ dst,
    const float* __restrict__ scale) {
  __shared__ float tile[32][33];
  int bx = blockIdx.x * 32;   // n-block
  int by = blockIdx.y * 32;   // k-block
  int tx = threadIdx.x & 31, ty = threadIdx.x >> 5;   // 32 x 8
#pragma unroll
  for (int r = 0; r < 32; r += 8)
    tile[ty + r][tx] = src[(size_t)(by + ty + r) * 1024 + bx + tx];
  __syncthreads();
  float sc = scale ? scale[by + tx] : 1.0f;
#pragma unroll
  for (int r = 0; r < 32; r += 8)
    dst[(size_t)(bx + ty + r) * 1024 + by + tx] = f2bf(tile[tx][ty + r] * sc);
}

// ---------------- MFMA GEMM core: m97 structure ----------------
// A: M x K bf16 (K contiguous). B: N x K bf16 (K contiguous, i.e. B^T).
// 128x128 tile / block, 4 waves in 2x2, 16x16x32 bf16 MFMA, BK=32.
__device__ __forceinline__ void gemm_accum(
    const ushort* __restrict__ A, const ushort* __restrict__ B,
    ushort* As, ushort* Bs, int tb, int nb, f32x4 acc[4][4]) {
  const int tid = threadIdx.x;
  const int w = tid >> 6, l = tid & 63;
  const int wrow = w & 1, wcol = w >> 1;
  const int lo = l & 15, q = l >> 4;
  const int rs = l >> 2;            // staging row within 16-row window
  const int cs = (l & 3) * 8;       // staging k offset (ushorts)
  for (int k0 = 0; k0 < KDIM; k0 += 32) {
#pragma unroll
    for (int i = 0; i < 2; ++i) {
      int win = w * 2 + i;
      int r = win * 16 + rs;
      gload16(A + (size_t)(tb + r) * KDIM + k0 + cs, As + win * 512);
      gload16(B + (size_t)(nb + r) * KDIM + k0 + cs, Bs + win * 512);
    }
    __syncthreads();
    bf16x8 af[4], bfr[4];
#pragma unroll
    for (int i = 0; i < 4; ++i) {
      af[i]  = *(const bf16x8*)(As + (wrow * 64 + i * 16 + lo) * 32 + q * 8);
      bfr[i] = *(const bf16x8*)(Bs + (wcol * 64 + i * 16 + lo) * 32 + q * 8);
    }
#pragma unroll
    for (int i = 0; i < 4; ++i)
#pragma unroll
      for (int j = 0; j < 4; ++j)
        acc[i][j] = __builtin_amdgcn_mfma_f32_16x16x32_bf16(af[i], bfr[j], acc[i][j], 0, 0, 0);
    __syncthreads();
  }
}

__device__ __forceinline__ void store_acc(float* __restrict__ O, int tb, int nb,
                                          f32x4 acc[4][4]) {
  const int tid = threadIdx.x;
  const int w = tid >> 6, l = tid & 63;
  const int wrow = w & 1, wcol = w >> 1;
  const int lo = l & 15, q = l >> 4;
#pragma unroll
  for (int i = 0; i < 4; ++i)
#pragma unroll
    for (int j = 0; j < 4; ++j) {
      int col = nb + wcol * 64 + j * 16 + lo;
#pragma unroll
      for (int r = 0; r < 4; ++r) {
        int row = tb + wrow * 64 + i * 16 + q * 4 + r;
        O[(size_t)row * HID + col] = acc[i][j][r];
      }
    }
}

__global__ __launch_bounds__(256) void gemm1(
    const ushort* __restrict__ A, const ushort* __restrict__ B, float* __restrict__ O) {
  __shared__ __align__(16) ushort As[4096], Bs[4096];
  f32x4 acc[4][4];
#pragma unroll
  for (int i = 0; i < 4; ++i)
#pragma unroll
    for (int j = 0; j < 4; ++j) acc[i][j] = (f32x4){0.f, 0.f, 0.f, 0.f};
  int tb = blockIdx.x * 128, nb = blockIdx.y * 128;
  gemm_accum(A, B, As, Bs, tb, nb, acc);
  store_acc(O, tb, nb, acc);
}

__global__ __launch_bounds__(256) void gemm3(
    const ushort* __restrict__ A1, const ushort* __restrict__ B1,
    const ushort* __restrict__ A2, const ushort* __restrict__ B2,
    const ushort* __restrict__ A3, const ushort* __restrict__ B3,
    float* __restrict__ O) {
  __shared__ __align__(16) ushort As[4096], Bs[4096];
  f32x4 acc[4][4];
#pragma unroll
  for (int i = 0; i < 4; ++i)
#pragma unroll
    for (int j = 0; j < 4; ++j) acc[i][j] = (f32x4){0.f, 0.f, 0.f, 0.f};
  int tb = blockIdx.x * 128, nb = blockIdx.y * 128;
  gemm_accum(A1, B1, As, Bs, tb, nb, acc);   // Hre @ Cre^T
  gemm_accum(A2, B2, As, Bs, tb, nb, acc);   // Him @ (-Cim)^T
  gemm_accum(A3, B3, As, Bs, tb, nb, acc);   // X @ D
  store_acc(O, tb, nb, acc);
}

// ---------------- scan pass 1: in-place local scans, write chunk sums ----------
__global__ __launch_bounds__(256) void scan_local(
    float* __restrict__ BuRe, float* __restrict__ BuIm,
    const float* __restrict__ lam_re, const float* __restrict__ lam_im,
    float* __restrict__ Sre, float* __restrict__ Sim) {
  int h = blockIdx.y * 256 + threadIdx.x;
  int c = blockIdx.x;
  float lr = lam_re[h], li = lam_im[h];
  float hr = 0.f, hi = 0.f;
  size_t base = (size_t)c * CHUNK * HID + h;
  for (int t = 0; t < CHUNK; ++t) {
    float br = BuRe[base + (size_t)t * HID];
    float bi = BuIm[base + (size_t)t * HID];
    float nr = fmaf(lr, hr, fmaf(-li, hi, br));
    float ni = fmaf(lr, hi, fmaf(li, hr, bi));
    BuRe[base + (size_t)t * HID] = nr;
    BuIm[base + (size_t)t * HID] = ni;
    hr = nr; hi = ni;
  }
  Sre[(size_t)c * HID + h] = hr;
  Sim[(size_t)c * HID + h] = hi;
}

// ---------------- scan pass 2: serial carry scan over chunks ----------------
__global__ __launch_bounds__(256) void scan_carry(
    const float* __restrict__ Sre, const float* __restrict__ Sim,
    const float* __restrict__ lam_re, const float* __restrict__ lam_im,
    float* __restrict__ Pre, float* __restrict__ Pim) {
  int h = blockIdx.x * 256 + threadIdx.x;
  float lr = lam_re[h], li = lam_im[h];
  float pr = lr, pi = li;       // lambda^128 via 7 squarings
#pragma unroll
  for (int s = 0; s < 7; ++s) {
    float nr = pr * pr - pi * pi;
    float ni = 2.f * pr * pi;
    pr = nr; pi = ni;
  }
  float cr = 0.f, ci = 0.f;
  for (int c = 0; c < NCHUNK; ++c) {
    Pre[(size_t)c * HID + h] = cr;
    Pim[(size_t)c * HID + h] = ci;
    float sr = Sre[(size_t)c * HID + h];
    float si = Sim[(size_t)c * HID + h];
    float nr = fmaf(pr, cr, fmaf(-pi, ci, sr));
    float ni = fmaf(pr, ci, fmaf(pi, cr, si));
    cr = nr; ci = ni;
  }
}

// ---------------- scan pass 3: add lambda^(j+1)*carry, emit bf16 H --------------
__global__ __launch_bounds__(256) void scan_fix(
    const float* __restrict__ Hre, const float* __restrict__ Him,
    const float* __restrict__ lam_re, const float* __restrict__ lam_im,
    const float* __restrict__ Pre, const float* __restrict__ Pim,
    ushort* __restrict__ HbfRe, ushort* __restrict__ HbfIm) {
  int h = blockIdx.y * 256 + threadIdx.x;
  int c = blockIdx.x;
  float lr = lam_re[h], li = lam_im[h];
  float qr = Pre[(size_t)c * HID + h];
  float qi = Pim[(size_t)c * HID + h];
  size_t base = (size_t)c * CHUNK * HID + h;
  for (int t = 0; t < CHUNK; ++t) {
    float nr = lr * qr - li * qi;
    float ni = lr * qi + li * qr;
    qr = nr; qi = ni;
    HbfRe[base + (size_t)t * HID] = f2bf(Hre[base + (size_t)t * HID] + qr);
    HbfIm[base + (size_t)t * HID] = f2bf(Him[base + (size_t)t * HID] + qi);
  }
}

extern "C" void kernel_launch(void* const* d_in, const int* in_sizes, int n_in,
                              void* d_out, int out_size, void* d_ws, size_t ws_size,
                              hipStream_t stream) {
  const float* inputs    = (const float*)d_in[0];
  const float* nu_log    = (const float*)d_in[1];
  const float* theta_log = (const float*)d_in[2];
  const float* gamma_log = (const float*)d_in[3];
  const float* B_re      = (const float*)d_in[4];
  const float* B_im      = (const float*)d_in[5];
  const float* C_re      = (const float*)d_in[6];
  const float* C_im      = (const float*)d_in[7];
  const float* D         = (const float*)d_in[8];
  float* out = (float*)d_out;

  char* ws = (char*)d_ws;
  constexpr size_t TH = (size_t)T_LEN * HID;       // 16.8M elems
  constexpr size_t W  = (size_t)1024 * 1024;       // weight elems
  constexpr size_t CH = (size_t)NCHUNK * HID;

  float*  BuRe  = (float*)(ws);                    // TH*4 B
  float*  BuIm  = (float*)(ws + TH * 4);           // TH*4 B
  ushort* Xbf   = (ushort*)(ws + TH * 8);          // TH*2 B
  ushort* HbfRe = (ushort*)(ws + TH * 10);         // TH*2 B
  ushort* HbfIm = (ushort*)(ws + TH * 12);         // TH*2 B
  char*   p     = ws + TH * 14;
  ushort* BreT  = (ushort*)(p);            p += W * 2;
  ushort* BimT  = (ushort*)(p);            p += W * 2;
  ushort* CreB  = (ushort*)(p);            p += W * 2;
  ushort* CimB  = (ushort*)(p);            p += W * 2;
  ushort* DT    = (ushort*)(p);            p += W * 2;
  float*  Sre   = (float*)(p);             p += CH * 4;
  float*  Sim   = (float*)(p);             p += CH * 4;
  float*  Pre   = (float*)(p);             p += CH * 4;
  float*  Pim   = (float*)(p);             p += CH * 4;
  float*  lamR  = (float*)(p);             p += 4096;
  float*  lamI  = (float*)(p);             p += 4096;
  float*  eg    = (float*)(p);             p += 4096;

  prep_kernel<<<dim3(HID / 256), 256, 0, stream>>>(nu_log, theta_log, gamma_log,
                                                   lamR, lamI, eg);
  // conversions
  convscale<<<dim3((unsigned)(TH / 4 / 256)), 256, 0, stream>>>(inputs, Xbf, 1.0f);
  transpose_bf<<<dim3(32, 32), 256, 0, stream>>>(B_re, BreT, eg);
  transpose_bf<<<dim3(32, 32), 256, 0, stream>>>(B_im, BimT, eg);
  convscale<<<dim3((unsigned)(W / 4 / 256)), 256, 0, stream>>>(C_re, CreB, 1.0f);
  convscale<<<dim3((unsigned)(W / 4 / 256)), 256, 0, stream>>>(C_im, CimB, -1.0f);
  transpose_bf<<<dim3(32, 32), 256, 0, stream>>>(D, DT, nullptr);

  // Bu = (X*eg) @ B  (eg folded into B rows)
  gemm1<<<dim3(T_LEN / 128, HID / 128), 256, 0, stream>>>(Xbf, BreT, BuRe);
  gemm1<<<dim3(T_LEN / 128, HID / 128), 256, 0, stream>>>(Xbf, BimT, BuIm);

  // scan
  scan_local<<<dim3(NCHUNK, HID / 256), 256, 0, stream>>>(BuRe, BuIm, lamR, lamI,
                                                          Sre, Sim);
  scan_carry<<<dim3(HID / 256), 256, 0, stream>>>(Sre, Sim, lamR, lamI, Pre, Pim);
  scan_fix<<<dim3(NCHUNK, HID / 256), 256, 0, stream>>>(BuRe, BuIm, lamR, lamI,
                                                        Pre, Pim, HbfRe, HbfIm);

  // out = Hre@Cre^T - Him@Cim^T + X@D
  gemm3<<<dim3(T_LEN / 128, HID / 128), 256, 0, stream>>>(HbfRe, CreB, HbfIm, CimB,
                                                          Xbf, DT, out);
}

// Round 3
// 460.421 us; speedup vs baseline: 5.4697x; 1.0492x over previous
//
#include <hip/hip_runtime.h>
#include <hip/hip_bf16.h>
#include <stdint.h>

#define T_LEN   16384
#define HID     1024
#define KDIM    1024
#define CHUNK   128
#define NCHUNK  128

typedef __bf16 bf16x8 __attribute__((ext_vector_type(8)));
typedef float  f32x4  __attribute__((ext_vector_type(4)));

__device__ inline ushort f2bf(float f) {
  union { float f; uint32_t u; } v; v.f = f;
  uint32_t r = v.u + 0x7FFF + ((v.u >> 16) & 1);   // RNE
  return (ushort)(r >> 16);
}
__device__ inline float bf2f(ushort u) {
  union { uint32_t u; float f; } v; v.u = ((uint32_t)u) << 16;
  return v.f;
}

__device__ inline void gload16(const void* g, void* l) {
  __builtin_amdgcn_global_load_lds(
      (const __attribute__((address_space(1))) void*)g,
      (__attribute__((address_space(3))) void*)l, 16, 0, 0);
}

// ---------------- prep: lambda (complex), exp(gamma) ----------------
__global__ __launch_bounds__(256) void prep_kernel(
    const float* __restrict__ nu_log, const float* __restrict__ theta_log,
    const float* __restrict__ gamma_log,
    float* __restrict__ lam_re, float* __restrict__ lam_im, float* __restrict__ eg) {
  int h = blockIdx.x * 256 + threadIdx.x;
  if (h < HID) {
    float mag = expf(-expf(nu_log[h]));
    float th  = expf(theta_log[h]);
    lam_re[h] = mag * cosf(th);
    lam_im[h] = mag * sinf(th);
    eg[h]     = expf(gamma_log[h]);
  }
}

// ---------------- fp32 -> bf16, vectorized x4 ----------------
__global__ __launch_bounds__(256) void convX(
    const float* __restrict__ src, ushort* __restrict__ dst) {
  size_t i = ((size_t)blockIdx.x * 256 + threadIdx.x) * 4;
  float4 v = *(const float4*)(src + i);
  ushort4 o;
  o.x = f2bf(v.x); o.y = f2bf(v.y); o.z = f2bf(v.z); o.w = f2bf(v.w);
  *(ushort4*)(dst + i) = o;
}

// ---------------- all weight prep in one kernel (z selects job) ----------------
// z=0: BreT[n*1024+k] = B_re[k*1024+n]*eg[k]   z=1: same for B_im
// z=2: CreB = bf16(C_re)                        z=3: CimB = bf16(-C_im)
// z=4: DT[n*1024+k] = D[k*1024+n]
__global__ __launch_bounds__(256) void weight_prep(
    const float* __restrict__ Bre, const float* __restrict__ Bim,
    const float* __restrict__ Cre, const float* __restrict__ Cim,
    const float* __restrict__ D,   const float* __restrict__ eg,
    ushort* __restrict__ BreT, ushort* __restrict__ BimT,
    ushort* __restrict__ CreB, ushort* __restrict__ CimB,
    ushort* __restrict__ DT) {
  __shared__ float tile[32][33];
  int z = blockIdx.z;
  if (z == 2 || z == 3) {                       // straight convert (C matrices)
    const float* src = (z == 2) ? Cre : Cim;
    ushort* dst = (z == 2) ? CreB : CimB;
    float s = (z == 2) ? 1.0f : -1.0f;
    size_t base = ((size_t)blockIdx.y * 32 + (threadIdx.x >> 3)) * 1024 +
                  blockIdx.x * 32 + (threadIdx.x & 7) * 4;
    float4 v = *(const float4*)(src + base);
    ushort4 o;
    o.x = f2bf(v.x * s); o.y = f2bf(v.y * s);
    o.z = f2bf(v.z * s); o.w = f2bf(v.w * s);
    *(ushort4*)(dst + base) = o;
    return;
  }
  const float* src = (z == 0) ? Bre : (z == 1) ? Bim : D;
  ushort* dst = (z == 0) ? BreT : (z == 1) ? BimT : DT;
  bool scaled = (z < 2);
  int bx = blockIdx.x * 32;   // n-block
  int by = blockIdx.y * 32;   // k-block
  int tx = threadIdx.x & 31, ty = threadIdx.x >> 5;   // 32 x 8
#pragma unroll
  for (int r = 0; r < 32; r += 8)
    tile[ty + r][tx] = src[(size_t)(by + ty + r) * 1024 + bx + tx];
  __syncthreads();
  float sc = scaled ? eg[by + tx] : 1.0f;
#pragma unroll
  for (int r = 0; r < 32; r += 8)
    dst[(size_t)(bx + ty + r) * 1024 + by + tx] = f2bf(tile[tx][ty + r] * sc);
}

// ---------------- MFMA GEMM core (m97 structure) ----------------
__device__ __forceinline__ void gemm_accum(
    const ushort* __restrict__ A, const ushort* __restrict__ B,
    ushort* As, ushort* Bs, int tb, int nb, f32x4 acc[4][4]) {
  const int tid = threadIdx.x;
  const int w = tid >> 6, l = tid & 63;
  const int wrow = w & 1, wcol = w >> 1;
  const int lo = l & 15, q = l >> 4;
  const int rs = l >> 2;
  const int cs = (l & 3) * 8;
  for (int k0 = 0; k0 < KDIM; k0 += 32) {
#pragma unroll
    for (int i = 0; i < 2; ++i) {
      int win = w * 2 + i;
      int r = win * 16 + rs;
      gload16(A + (size_t)(tb + r) * KDIM + k0 + cs, As + win * 512);
      gload16(B + (size_t)(nb + r) * KDIM + k0 + cs, Bs + win * 512);
    }
    __syncthreads();
    bf16x8 af[4], bfr[4];
#pragma unroll
    for (int i = 0; i < 4; ++i) {
      af[i]  = *(const bf16x8*)(As + (wrow * 64 + i * 16 + lo) * 32 + q * 8);
      bfr[i] = *(const bf16x8*)(Bs + (wcol * 64 + i * 16 + lo) * 32 + q * 8);
    }
#pragma unroll
    for (int i = 0; i < 4; ++i)
#pragma unroll
      for (int j = 0; j < 4; ++j)
        acc[i][j] = __builtin_amdgcn_mfma_f32_16x16x32_bf16(af[i], bfr[j], acc[i][j], 0, 0, 0);
    __syncthreads();
  }
}

// ---------------- dual-B GEMM: BuRe/BuIm bf16 in one pass ----------------
__global__ __launch_bounds__(256) void gemm_bu(
    const ushort* __restrict__ A, const ushort* __restrict__ B1,
    const ushort* __restrict__ B2,
    ushort* __restrict__ O1, ushort* __restrict__ O2) {
  __shared__ __align__(16) ushort As[4096], Bs1[4096], Bs2[4096];
  f32x4 acc1[4][4], acc2[4][4];
#pragma unroll
  for (int i = 0; i < 4; ++i)
#pragma unroll
    for (int j = 0; j < 4; ++j) {
      acc1[i][j] = (f32x4){0.f, 0.f, 0.f, 0.f};
      acc2[i][j] = (f32x4){0.f, 0.f, 0.f, 0.f};
    }
  const int tid = threadIdx.x;
  const int w = tid >> 6, l = tid & 63;
  const int wrow = w & 1, wcol = w >> 1;
  const int lo = l & 15, q = l >> 4;
  const int rs = l >> 2;
  const int cs = (l & 3) * 8;
  const int tb = blockIdx.x * 128, nb = blockIdx.y * 128;
  for (int k0 = 0; k0 < KDIM; k0 += 32) {
#pragma unroll
    for (int i = 0; i < 2; ++i) {
      int win = w * 2 + i;
      int r = win * 16 + rs;
      gload16(A  + (size_t)(tb + r) * KDIM + k0 + cs, As  + win * 512);
      gload16(B1 + (size_t)(nb + r) * KDIM + k0 + cs, Bs1 + win * 512);
      gload16(B2 + (size_t)(nb + r) * KDIM + k0 + cs, Bs2 + win * 512);
    }
    __syncthreads();
    bf16x8 af[4], b1[4], b2[4];
#pragma unroll
    for (int i = 0; i < 4; ++i) {
      af[i] = *(const bf16x8*)(As  + (wrow * 64 + i * 16 + lo) * 32 + q * 8);
      b1[i] = *(const bf16x8*)(Bs1 + (wcol * 64 + i * 16 + lo) * 32 + q * 8);
      b2[i] = *(const bf16x8*)(Bs2 + (wcol * 64 + i * 16 + lo) * 32 + q * 8);
    }
#pragma unroll
    for (int i = 0; i < 4; ++i)
#pragma unroll
      for (int j = 0; j < 4; ++j) {
        acc1[i][j] = __builtin_amdgcn_mfma_f32_16x16x32_bf16(af[i], b1[j], acc1[i][j], 0, 0, 0);
        acc2[i][j] = __builtin_amdgcn_mfma_f32_16x16x32_bf16(af[i], b2[j], acc2[i][j], 0, 0, 0);
      }
    __syncthreads();
  }
#pragma unroll
  for (int i = 0; i < 4; ++i)
#pragma unroll
    for (int j = 0; j < 4; ++j) {
      int col = nb + wcol * 64 + j * 16 + lo;
#pragma unroll
      for (int r = 0; r < 4; ++r) {
        int row = tb + wrow * 64 + i * 16 + q * 4 + r;
        O1[(size_t)row * HID + col] = f2bf(acc1[i][j][r]);
        O2[(size_t)row * HID + col] = f2bf(acc2[i][j][r]);
      }
    }
}

// ---------------- out = Hre@Cre^T + Him@(-Cim)^T + X@D^T ----------------
__global__ __launch_bounds__(256) void gemm3(
    const ushort* __restrict__ A1, const ushort* __restrict__ B1,
    const ushort* __restrict__ A2, const ushort* __restrict__ B2,
    const ushort* __restrict__ A3, const ushort* __restrict__ B3,
    float* __restrict__ O) {
  __shared__ __align__(16) ushort As[4096], Bs[4096];
  f32x4 acc[4][4];
#pragma unroll
  for (int i = 0; i < 4; ++i)
#pragma unroll
    for (int j = 0; j < 4; ++j) acc[i][j] = (f32x4){0.f, 0.f, 0.f, 0.f};
  int tb = blockIdx.x * 128, nb = blockIdx.y * 128;
  gemm_accum(A1, B1, As, Bs, tb, nb, acc);
  gemm_accum(A2, B2, As, Bs, tb, nb, acc);
  gemm_accum(A3, B3, As, Bs, tb, nb, acc);
  const int tid = threadIdx.x;
  const int w = tid >> 6, l = tid & 63;
  const int wrow = w & 1, wcol = w >> 1;
  const int lo = l & 15, q = l >> 4;
#pragma unroll
  for (int i = 0; i < 4; ++i)
#pragma unroll
    for (int j = 0; j < 4; ++j) {
      int col = nb + wcol * 64 + j * 16 + lo;
#pragma unroll
      for (int r = 0; r < 4; ++r) {
        int row = tb + wrow * 64 + i * 16 + q * 4 + r;
        O[(size_t)row * HID + col] = acc[i][j][r];
      }
    }
}

// ---------------- scan pass A: chunk sums only (registers, no writeback) -------
// 2 h per thread (uint loads), 2 interleaved complex chains
__global__ __launch_bounds__(256) void scan_sums(
    const ushort* __restrict__ BuRe, const ushort* __restrict__ BuIm,
    const float* __restrict__ lam_re, const float* __restrict__ lam_im,
    float* __restrict__ Sre, float* __restrict__ Sim) {
  int h0 = (blockIdx.y * 256 + threadIdx.x) * 2;
  int c = blockIdx.x;
  float lr0 = lam_re[h0], li0 = lam_im[h0];
  float lr1 = lam_re[h0 + 1], li1 = lam_im[h0 + 1];
  float hr0 = 0.f, hi0 = 0.f, hr1 = 0.f, hi1 = 0.f;
  size_t base = ((size_t)c * CHUNK * HID + h0) >> 1;   // uint index
  const uint* Re = (const uint*)BuRe;
  const uint* Im = (const uint*)BuIm;
#pragma unroll 4
  for (int t = 0; t < CHUNK; ++t) {
    uint re = Re[base + (size_t)t * (HID / 2)];
    uint im = Im[base + (size_t)t * (HID / 2)];
    float br0 = bf2f((ushort)re), br1 = bf2f((ushort)(re >> 16));
    float bi0 = bf2f((ushort)im), bi1 = bf2f((ushort)(im >> 16));
    float nr0 = fmaf(lr0, hr0, fmaf(-li0, hi0, br0));
    float ni0 = fmaf(lr0, hi0, fmaf(li0, hr0, bi0));
    float nr1 = fmaf(lr1, hr1, fmaf(-li1, hi1, br1));
    float ni1 = fmaf(lr1, hi1, fmaf(li1, hr1, bi1));
    hr0 = nr0; hi0 = ni0; hr1 = nr1; hi1 = ni1;
  }
  Sre[(size_t)c * HID + h0] = hr0;  Sre[(size_t)c * HID + h0 + 1] = hr1;
  Sim[(size_t)c * HID + h0] = hi0;  Sim[(size_t)c * HID + h0 + 1] = hi1;
}

// ---------------- scan pass 2: serial carry scan over chunks ----------------
__global__ __launch_bounds__(256) void scan_carry(
    const float* __restrict__ Sre, const float* __restrict__ Sim,
    const float* __restrict__ lam_re, const float* __restrict__ lam_im,
    float* __restrict__ Pre, float* __restrict__ Pim) {
  int h = blockIdx.x * 256 + threadIdx.x;
  float lr = lam_re[h], li = lam_im[h];
  float pr = lr, pi = li;       // lambda^128 via 7 squarings
#pragma unroll
  for (int s = 0; s < 7; ++s) {
    float nr = pr * pr - pi * pi;
    float ni = 2.f * pr * pi;
    pr = nr; pi = ni;
  }
  float cr = 0.f, ci = 0.f;
  for (int c = 0; c < NCHUNK; ++c) {
    Pre[(size_t)c * HID + h] = cr;
    Pim[(size_t)c * HID + h] = ci;
    float sr = Sre[(size_t)c * HID + h];
    float si = Sim[(size_t)c * HID + h];
    float nr = fmaf(pr, cr, fmaf(-pi, ci, sr));
    float ni = fmaf(pr, ci, fmaf(pi, cr, si));
    cr = nr; ci = ni;
  }
}

// ---------------- scan pass B: replay with carry init, emit bf16 H -------------
__global__ __launch_bounds__(256) void scan_emit(
    const ushort* __restrict__ BuRe, const ushort* __restrict__ BuIm,
    const float* __restrict__ lam_re, const float* __restrict__ lam_im,
    const float* __restrict__ Pre, const float* __restrict__ Pim,
    ushort* __restrict__ HbfRe, ushort* __restrict__ HbfIm) {
  int h0 = (blockIdx.y * 256 + threadIdx.x) * 2;
  int c = blockIdx.x;
  float lr0 = lam_re[h0], li0 = lam_im[h0];
  float lr1 = lam_re[h0 + 1], li1 = lam_im[h0 + 1];
  float hr0 = Pre[(size_t)c * HID + h0], hi0 = Pim[(size_t)c * HID + h0];
  float hr1 = Pre[(size_t)c * HID + h0 + 1], hi1 = Pim[(size_t)c * HID + h0 + 1];
  size_t base = ((size_t)c * CHUNK * HID + h0) >> 1;
  const uint* Re = (const uint*)BuRe;
  const uint* Im = (const uint*)BuIm;
  uint* ORe = (uint*)HbfRe;
  uint* OIm = (uint*)HbfIm;
#pragma unroll 4
  for (int t = 0; t < CHUNK; ++t) {
    uint re = Re[base + (size_t)t * (HID / 2)];
    uint im = Im[base + (size_t)t * (HID / 2)];
    float br0 = bf2f((ushort)re), br1 = bf2f((ushort)(re >> 16));
    float bi0 = bf2f((ushort)im), bi1 = bf2f((ushort)(im >> 16));
    float nr0 = fmaf(lr0, hr0, fmaf(-li0, hi0, br0));
    float ni0 = fmaf(lr0, hi0, fmaf(li0, hr0, bi0));
    float nr1 = fmaf(lr1, hr1, fmaf(-li1, hi1, br1));
    float ni1 = fmaf(lr1, hi1, fmaf(li1, hr1, bi1));
    hr0 = nr0; hi0 = ni0; hr1 = nr1; hi1 = ni1;
    ORe[base + (size_t)t * (HID / 2)] = (uint)f2bf(hr0) | ((uint)f2bf(hr1) << 16);
    OIm[base + (size_t)t * (HID / 2)] = (uint)f2bf(hi0) | ((uint)f2bf(hi1) << 16);
  }
}

extern "C" void kernel_launch(void* const* d_in, const int* in_sizes, int n_in,
                              void* d_out, int out_size, void* d_ws, size_t ws_size,
                              hipStream_t stream) {
  const float* inputs    = (const float*)d_in[0];
  const float* nu_log    = (const float*)d_in[1];
  const float* theta_log = (const float*)d_in[2];
  const float* gamma_log = (const float*)d_in[3];
  const float* B_re      = (const float*)d_in[4];
  const float* B_im      = (const float*)d_in[5];
  const float* C_re      = (const float*)d_in[6];
  const float* C_im      = (const float*)d_in[7];
  const float* D         = (const float*)d_in[8];
  float* out = (float*)d_out;

  char* ws = (char*)d_ws;
  constexpr size_t TH = (size_t)T_LEN * HID;       // 16.8M elems
  constexpr size_t W  = (size_t)1024 * 1024;
  constexpr size_t CH = (size_t)NCHUNK * HID;

  ushort* Xbf   = (ushort*)(ws);                   // TH*2
  ushort* BuRe  = (ushort*)(ws + TH * 2);
  ushort* BuIm  = (ushort*)(ws + TH * 4);
  ushort* HbfRe = (ushort*)(ws + TH * 6);
  ushort* HbfIm = (ushort*)(ws + TH * 8);
  char*   p     = ws + TH * 10;
  ushort* BreT  = (ushort*)(p);            p += W * 2;
  ushort* BimT  = (ushort*)(p);            p += W * 2;
  ushort* CreB  = (ushort*)(p);            p += W * 2;
  ushort* CimB  = (ushort*)(p);            p += W * 2;
  ushort* DT    = (ushort*)(p);            p += W * 2;
  float*  Sre   = (float*)(p);             p += CH * 4;
  float*  Sim   = (float*)(p);             p += CH * 4;
  float*  Pre   = (float*)(p);             p += CH * 4;
  float*  Pim   = (float*)(p);             p += CH * 4;
  float*  lamR  = (float*)(p);             p += 4096;
  float*  lamI  = (float*)(p);             p += 4096;
  float*  eg    = (float*)(p);             p += 4096;

  prep_kernel<<<dim3(HID / 256), 256, 0, stream>>>(nu_log, theta_log, gamma_log,
                                                   lamR, lamI, eg);
  convX<<<dim3((unsigned)(TH / 4 / 256)), 256, 0, stream>>>(inputs, Xbf);
  weight_prep<<<dim3(32, 32, 5), 256, 0, stream>>>(B_re, B_im, C_re, C_im, D, eg,
                                                   BreT, BimT, CreB, CimB, DT);

  gemm_bu<<<dim3(T_LEN / 128, HID / 128), 256, 0, stream>>>(Xbf, BreT, BimT,
                                                            BuRe, BuIm);

  scan_sums<<<dim3(NCHUNK, HID / 512), 256, 0, stream>>>(BuRe, BuIm, lamR, lamI,
                                                         Sre, Sim);
  scan_carry<<<dim3(HID / 256), 256, 0, stream>>>(Sre, Sim, lamR, lamI, Pre, Pim);
  scan_emit<<<dim3(NCHUNK, HID / 512), 256, 0, stream>>>(BuRe, BuIm, lamR, lamI,
                                                         Pre, Pim, HbfRe, HbfIm);

  gemm3<<<dim3(T_LEN / 128, HID / 128), 256, 0, stream>>>(HbfRe, CreB, HbfIm, CimB,
                                                          Xbf, DT, out);
}